// Round 9
// baseline (393.195 us; speedup 1.0000x reference)
//
#include <hip/hip_runtime.h>
#include <cstddef>
#include <cstdint>

#define N_NODES 10000
#define N_EDGES 160000
#define NWAVES  8192   // node_agg: 2048 blocks x 4 waves, persistent grid-stride

// ---- constants ----
#define RS8    0.35355339059327373f   // 1/sqrt(8)
#define RS32   0.17677669529663687f   // 1/sqrt(32)
#define RS96   0.10206207261596575f   // 1/sqrt(96)
#define RS128  0.08838834764831845f   // 1/sqrt(128)
#define RS3    0.5773502691896258f    // 1/sqrt(3)
#define SQ3_   1.7320508075688772f
#define SQ5_   2.23606797749979f
#define A_     0.18257418583505536f   // 1/sqrt(30)
#define B_     0.31622776601683794f   // 1/sqrt(10)
#define SILU_C_ 1.6765208f
#define CS_    0.3826834323650898f    // sin(pi/8)
#define CX_    0.9238795325112867f    // cos(pi/8)
#define QDEG   0.25f                  // 1/sqrt(16)

typedef __attribute__((ext_vector_type(8))) short bf16x8;
typedef __attribute__((ext_vector_type(4))) float f32x4;

__device__ inline float bf2f(unsigned v) {
  union { unsigned u; float f; } c; c.u = v << 16; return c.f;
}
__device__ inline float bfhi(unsigned v) {   // float from HIGH 16 bits
  union { unsigned u; float f; } c; c.u = v & 0xffff0000u; return c.f;
}
__device__ inline unsigned short f2bf(float f) {
  union { float f; unsigned u; } c; c.f = f;
  unsigned r = c.u + 0x7fff + ((c.u >> 16) & 1);
  return (unsigned short)(r >> 16);
}
__device__ inline unsigned pack2bf(float a, float b) {
  return (unsigned)f2bf(a) | ((unsigned)f2bf(b) << 16);
}

// zero counts + build fc1p (fc1 64x320 f32 -> bf16 MFMA B-fragment order)
__global__ void k_init(int* __restrict__ counts, const float* __restrict__ fc1,
                       unsigned short* __restrict__ fc1p) {
  int i = blockIdx.x * blockDim.x + threadIdx.x;
  if (i < N_NODES) counts[i] = 0;
  if (i < 20480) {
    int j = i & 7, q = (i >> 3) & 3, n = (i >> 5) & 15, kq = (i >> 9) & 1, t = i >> 10;
    int k = kq * 32 + q * 8 + j;
    fc1p[i] = f2bf(fc1[k * 320 + t * 16 + n]);
  }
}

__global__ void k_hist(const int* __restrict__ edst, int* __restrict__ counts) {
  int e = blockIdx.x * blockDim.x + threadIdx.x;
  if (e < N_EDGES) atomicAdd(&counts[edst[e]], 1);
}

// exclusive scan of counts -> offs/cur; degree histogram + descending-degree
// exclusive scan -> dcur (single block).
__global__ __launch_bounds__(256) void k_scan(const int* __restrict__ counts,
                                              int* __restrict__ offs,
                                              int* __restrict__ cur,
                                              int* __restrict__ dcur) {
  __shared__ int ps[256];
  __shared__ int dbin[256];
  int t = threadIdx.x;
  dbin[t] = 0;
  int base = t * 40;
  int sum = 0;
  for (int i = 0; i < 40; ++i) {
    int idx = base + i;
    if (idx < N_NODES) sum += counts[idx];
  }
  ps[t] = sum;
  __syncthreads();
  for (int off = 1; off < 256; off <<= 1) {
    int v = (t >= off) ? ps[t - off] : 0;
    __syncthreads();
    ps[t] += v;
    __syncthreads();
  }
  int run = (t == 0) ? 0 : ps[t - 1];
  for (int i = 0; i < 40; ++i) {
    int idx = base + i;
    if (idx < N_NODES) {
      int c = counts[idx];
      offs[idx] = run; cur[idx] = run;
      run += c;
      atomicAdd(&dbin[c < 255 ? c : 255], 1);
    }
  }
  __syncthreads();
  int rb = 255 - t;
  int v = dbin[rb];
  __syncthreads();
  ps[t] = v;
  __syncthreads();
  for (int off = 1; off < 256; off <<= 1) {
    int u = (t >= off) ? ps[t - off] : 0;
    __syncthreads();
    ps[t] += u;
    __syncthreads();
  }
  dcur[rb] = ps[t] - v;
}

// edge scatter (sorted-by-dst) + node scatter (descending-degree order).
// Rank-indexed node metadata: order/obeg/ocnt so node_agg's header is 3
// independent scalar loads.
__global__ void k_scatter(const int* __restrict__ edst, int* __restrict__ cur,
                          int* __restrict__ sorted, const int* __restrict__ counts,
                          const int* __restrict__ offs,
                          int* __restrict__ dcur, int* __restrict__ order,
                          int* __restrict__ obeg, int* __restrict__ ocnt) {
  int e = blockIdx.x * blockDim.x + threadIdx.x;
  if (e < N_EDGES) {
    int d = edst[e];
    int p = atomicAdd(&cur[d], 1);
    sorted[p] = e;
  }
  if (e < N_NODES) {
    int c = counts[e];
    int b = c < 255 ? c : 255;
    int p = atomicAdd(&dcur[b], 1);
    order[p] = e; obeg[p] = offs[e]; ocnt[p] = c;
  }
}

// s[n][0:160], y[n][0:160]
__global__ void node_pre(const float* __restrict__ xin, const float* __restrict__ attr,
                         const float* __restrict__ sc_w0, const float* __restrict__ sc_w1,
                         const float* __restrict__ l1_w0, const float* __restrict__ l1_w1,
                         float* __restrict__ s, float* __restrict__ y) {
  int idx = blockIdx.x * blockDim.x + threadIdx.x;
  int n = idx / 160, c = idx - n * 160;
  const float* xr = xin + (size_t)n * 160;
  float a = attr[n];
  float sv, yv;
  if (c < 64) {
    float s_ = 0.f, y_ = 0.f;
    #pragma unroll 8
    for (int u = 0; u < 64; ++u) {
      float x = xr[u];
      s_ += x * sc_w0[u * 64 + c];
      y_ += x * l1_w0[u * 64 + c];
    }
    sv = s_ * a * 0.125f; yv = y_ * a * 0.125f;
  } else {
    int t = c - 64; int v = t / 3, i = t - v * 3;
    float s_ = 0.f, y_ = 0.f;
    #pragma unroll 8
    for (int u = 0; u < 32; ++u) {
      float x = xr[64 + u * 3 + i];
      s_ += x * sc_w1[u * 32 + v];
      y_ += x * l1_w1[u * 32 + v];
    }
    sv = s_ * a * RS32; yv = y_ * a * RS32;
  }
  s[idx] = sv; y[idx] = yv;
}

// MFMA bf16 radial GEMM over 64 SORTED edges per block.
// wbuf2 PACKED layout per edge (640 B):
//   bytes [0,256):   AB interleaved: u16[2c]=w[c], u16[2c+1]=w[64+c]
//   bytes [256,384): C: u16[c]=w[128+c]
//   bytes [384,640): DEFG interleaved: u16 at 384+8k: {w[192+k],w[224+k],w[256+k],w[288+k]}
// ed2 (stride 16 floats): [0..8]=SH, [9]=src id (int bits).
__device__ inline f32x4 wtile(const unsigned short* __restrict__ fc1p,
                              bf16x8 a0, bf16x8 a1, int mrow, int quad, int t) {
  f32x4 acc = {0.f, 0.f, 0.f, 0.f};
  bf16x8 b0 = *(const bf16x8*)(fc1p + ((size_t)((t * 2 + 0) * 16 + mrow) * 4 + quad) * 8);
  bf16x8 b1 = *(const bf16x8*)(fc1p + ((size_t)((t * 2 + 1) * 16 + mrow) * 4 + quad) * 8);
  acc = __builtin_amdgcn_mfma_f32_16x16x32_bf16(b0, a0, acc, 0, 0, 0);
  acc = __builtin_amdgcn_mfma_f32_16x16x32_bf16(b1, a1, acc, 0, 0, 0);
  return acc;
}

__global__ __launch_bounds__(256) void w_gemm(
    const float* __restrict__ ele, const float* __restrict__ fc0,
    const int* __restrict__ sorted, const int* __restrict__ esrc,
    const float* __restrict__ eattr, const unsigned short* __restrict__ fc1p,
    unsigned short* __restrict__ wout, float* __restrict__ ed2) {
  __shared__ int sh_ids[64];
  __shared__ __align__(16) float sh_ele[64][8];
  __shared__ __align__(16) float sh_ed[64 * 12];
  __shared__ __align__(16) unsigned short sh_h[64 * 72];  // 72-stride pad
  int t = threadIdx.x;
  int eb = blockIdx.x * 64;

  if (t < 64) sh_ids[t] = sorted[eb + t];
  __syncthreads();
  if (t < 128) {
    int e = t >> 1, hh = t & 1;
    ((float4*)&sh_ele[e][0])[hh] = ((const float4*)(ele + (size_t)sh_ids[e] * 8))[hh];
  }
  for (int i = t; i < 576; i += 256) {
    int e = i / 9, k = i - e * 9;
    sh_ed[e * 12 + k] = eattr[(size_t)sh_ids[e] * 9 + k];
  }
  if (t < 64) {
    ((int*)sh_ed)[t * 12 + 9] = esrc[sh_ids[t]];
    sh_ed[t * 12 + 10] = 0.f; sh_ed[t * 12 + 11] = 0.f;
  }
  __syncthreads();
  // ed2 write: 3 float4 per edge (stride 16 floats; slots 12..15 unused)
  if (t < 192) {
    int e = t / 3, q = t - e * 3;
    ((float4*)(ed2 + (size_t)(eb + e) * 16))[q] = ((const float4*)(sh_ed + e * 12))[q];
  }
  // h = silu(ele@fc0/sqrt8)*SILU_C -> bf16, A-layout [edge][k], stride 72
  #pragma unroll
  for (int ii = 0; ii < 16; ++ii) {
    int idx = t + ii * 256;
    int e = idx >> 6, k = idx & 63;
    float acc = 0.f;
    #pragma unroll
    for (int m = 0; m < 8; ++m) acc += sh_ele[e][m] * fc0[m * 64 + k];
    acc *= RS8;
    float hv = SILU_C_ * acc / (1.f + __expf(-acc));
    sh_h[e * 72 + k] = f2bf(hv);
  }
  __syncthreads();

  int wv = t >> 6, lane = t & 63;
  int m0 = wv * 16;
  int mrow = lane & 15, quad = lane >> 4;
  bf16x8 a0 = *(const bf16x8*)(sh_h + (m0 + mrow) * 72 + quad * 8);
  bf16x8 a1 = *(const bf16x8*)(sh_h + (m0 + mrow) * 72 + 32 + quad * 8);
  char* wbase = (char*)wout + (size_t)(eb + m0 + mrow) * 640;
  const float K = 0.125f;
  // AB region: tile pairs (t, t+4), channels j=16t+4q+r and j+64
  #pragma unroll
  for (int tt = 0; tt < 4; ++tt) {
    f32x4 Av = wtile(fc1p, a0, a1, mrow, quad, tt);
    f32x4 Bv = wtile(fc1p, a0, a1, mrow, quad, tt + 4);
    uint4 st;
    st.x = pack2bf(Av[0] * K, Bv[0] * K);
    st.y = pack2bf(Av[1] * K, Bv[1] * K);
    st.z = pack2bf(Av[2] * K, Bv[2] * K);
    st.w = pack2bf(Av[3] * K, Bv[3] * K);
    *(uint4*)(wbase + 64 * tt + 16 * quad) = st;
  }
  // C region: tiles 8..11, channels j=16t+4q+r (j-128 in [0,64))
  #pragma unroll
  for (int tt = 8; tt < 12; ++tt) {
    f32x4 Cv = wtile(fc1p, a0, a1, mrow, quad, tt);
    uint2 st;
    st.x = pack2bf(Cv[0] * K, Cv[1] * K);
    st.y = pack2bf(Cv[2] * K, Cv[3] * K);
    *(uint2*)(wbase + 256 + 32 * (tt - 8) + 8 * quad) = st;
  }
  // DEFG region: tile quads {t, t+2, t+4, t+6} for t=12,13; k=16(t-12)+4q+r
  #pragma unroll
  for (int tt = 12; tt < 14; ++tt) {
    f32x4 Dv = wtile(fc1p, a0, a1, mrow, quad, tt);
    f32x4 Ev = wtile(fc1p, a0, a1, mrow, quad, tt + 2);
    f32x4 Fv = wtile(fc1p, a0, a1, mrow, quad, tt + 4);
    f32x4 Gv = wtile(fc1p, a0, a1, mrow, quad, tt + 6);
    char* db = wbase + 384 + 128 * (tt - 12) + 32 * quad;
    uint4 s0, s1;
    s0.x = pack2bf(Dv[0] * K, Ev[0] * K); s0.y = pack2bf(Fv[0] * K, Gv[0] * K);
    s0.z = pack2bf(Dv[1] * K, Ev[1] * K); s0.w = pack2bf(Fv[1] * K, Gv[1] * K);
    s1.x = pack2bf(Dv[2] * K, Ev[2] * K); s1.y = pack2bf(Fv[2] * K, Gv[2] * K);
    s1.z = pack2bf(Dv[3] * K, Ev[3] * K); s1.w = pack2bf(Fv[3] * K, Gv[3] * K);
    *(uint4*)(db) = s0;
    *(uint4*)(db + 16) = s1;
  }
}

__device__ inline float lin2_col(const float* __restrict__ sm,
                                 const float* __restrict__ w0,
                                 const float* __restrict__ w1,
                                 const float* __restrict__ w2,
                                 const float* __restrict__ srow,
                                 float a, int oc) {
  if (oc < 64) {
    float o = 0.f;
    #pragma unroll 8
    for (int u = 0; u < 96; ++u) o += sm[u] * w0[u * 64 + oc];
    return CS_ * srow[oc] + CX_ * (o * a * RS96);
  } else if (oc < 160) {
    int t = oc - 64, v = t / 3, i = t - v * 3;
    float o = 0.f;
    #pragma unroll 8
    for (int u = 0; u < 128; ++u) o += sm[96 + u * 3 + i] * w1[u * 32 + v];
    return CS_ * srow[oc] + CX_ * (o * a * RS128);
  } else {
    int t = oc - 160, v = t / 5, k = t - v * 5;
    float o = 0.f;
    #pragma unroll 8
    for (int u = 0; u < 96; ++u) o += sm[480 + u * 5 + k] * w2[u * 32 + v];
    return o * a * RS96;
  }
}

// PERSISTENT: 2048 blocks x 4 waves; grid-stride over degree-ordered nodes.
// SH+src per edge arrive via SCALAR s_loads (uniform ed2 rows) -> SGPRs;
// y/w loads are saddr-form with fixed per-lane voffsets (no per-edge address
// VALU). Depth-3 vector prefetch (distance 2 iters), depth-1 scalar prefetch.
#define WREG 960
__global__ __launch_bounds__(256) void node_agg(
    const float* __restrict__ y, const float* __restrict__ s,
    const float* __restrict__ attr, const float* __restrict__ ed2,
    const unsigned short* __restrict__ wbuf,
    const int* __restrict__ order, const int* __restrict__ obeg,
    const int* __restrict__ ocnt,
    const float* __restrict__ w0, const float* __restrict__ w1,
    const float* __restrict__ w2, float* __restrict__ out) {
  __shared__ __align__(16) float smem[4 * WREG];
  int tid = threadIdx.x, wid = tid >> 6, lane = tid & 63, l31 = lane & 31;
  float* R = smem + wid * WREG;
  int gw = blockIdx.x * 4 + wid;
  // fixed per-lane byte offsets (loop-invariant)
  int voY  = 4 * lane;               // y scalar block
  int voX  = (64 + 3 * l31) * 4;     // y vector block (x0; x1,x2 via +4,+8)
  int voAB = 4 * lane;               // wbuf AB
  int voC  = 256 + 2 * lane;         // wbuf C
  int voDG = 384 + 8 * l31;          // wbuf DEFG

#define ISSUE_E(S, idx)                                                        \
  if ((idx) < cnt) {                                                           \
    const float4* ep = (const float4*)(ed2 + (size_t)(beg + (idx)) * 16);      \
    PE0##S = ep[0]; PE1##S = ep[1]; PE2##S = ep[2];                            \
  }

#define ISSUE_V(S, idx)                                                        \
  if ((idx) < cnt) {                                                           \
    int srcu = __builtin_amdgcn_readfirstlane(__float_as_int(PE2##S.y));       \
    const char* yb = (const char*)(y + (size_t)srcu * 160);                    \
    Y##S  = *(const float*)(yb + voY);                                         \
    X0##S = *(const float*)(yb + voX);                                         \
    X1##S = *(const float*)(yb + voX + 4);                                     \
    X2##S = *(const float*)(yb + voX + 8);                                     \
    const char* wb = (const char*)wbuf + (size_t)(beg + (idx)) * 640;          \
    AB##S = *(const unsigned*)(wb + voAB);                                     \
    Cw##S = *(const unsigned short*)(wb + voC);                                \
    DG##S = *(const uint2*)(wb + voDG);                                        \
  }

#define COMPUTE(S)                                                             \
  {                                                                            \
    float e0 = PE0##S.x, ey = PE0##S.y, ez = PE0##S.z, ex = PE0##S.w;          \
    float q0 = PE1##S.x, q1 = PE1##S.y, q2 = PE1##S.z, q3 = PE1##S.w;          \
    float q4 = PE2##S.x;                                                       \
    float Yv = Y##S, x0 = X0##S, x1 = X1##S, x2 = X2##S;                       \
    float vA = bf2f(AB##S), vB = bfhi(AB##S), vC = bf2f(Cw##S);                \
    float vD = bf2f(DG##S.x), vE = bfhi(DG##S.x);                              \
    float vF = bf2f(DG##S.y), vG = bfhi(DG##S.y);                              \
    aK0 += Yv * e0 * vA;                                                       \
    float tB = Yv * vB; aK2x += tB * ey; aK2y += tB * ez; aK2z += tB * ex;     \
    float tC = Yv * vC;                                                        \
    aK5a += tC * q0; aK5b += tC * q1; aK5c += tC * q2;                         \
    aK5d += tC * q3; aK5e += tC * q4;                                          \
    float t1 = x0 * ey + x1 * ez + x2 * ex; aK1 += (RS3 * vE) * t1;            \
    float s3 = e0 * vD; aK3x += x0 * s3; aK3y += x1 * s3; aK3z += x2 * s3;     \
    float s4 = SQ3_ * vG;                                                      \
    aK4x += s4 * (B_ * (x2 * q0 + x1 * q1 - x0 * q4) - A_ * x0 * q2);          \
    aK4y += s4 * (B_ * (x0 * q1 + x2 * q3) + 2.f * A_ * x1 * q2);              \
    aK4z += s4 * (B_ * (x0 * q0 + x1 * q3 + x2 * q4) - A_ * x2 * q2);          \
    float s6 = SQ5_ * vF;                                                      \
    aK6a += s6 * (-B_ * (x0 * ex + x2 * ey));                                  \
    aK6b += s6 * (-B_ * (x0 * ez + x1 * ey));                                  \
    aK6c += s6 * ( A_ * (x0 * ey + x2 * ex - 2.f * x1 * ez));                  \
    aK6d += s6 * (-B_ * (x1 * ex + x2 * ez));                                  \
    aK6e += s6 * ( B_ * (x0 * ey - x2 * ex));                                  \
  }
#define LWAIT __asm__ volatile("s_waitcnt lgkmcnt(0)" ::: "memory")

  for (int ni = gw; ni < N_NODES; ni += NWAVES) {
    int n   = __builtin_amdgcn_readfirstlane(order[ni]);
    int beg = __builtin_amdgcn_readfirstlane(obeg[ni]);
    int cnt = __builtin_amdgcn_readfirstlane(ocnt[ni]);

    float aK0 = 0.f, aK2x = 0.f, aK2y = 0.f, aK2z = 0.f;
    float aK5a = 0.f, aK5b = 0.f, aK5c = 0.f, aK5d = 0.f, aK5e = 0.f;
    float aK1 = 0.f, aK3x = 0.f, aK3y = 0.f, aK3z = 0.f;
    float aK4x = 0.f, aK4y = 0.f, aK4z = 0.f;
    float aK6a = 0.f, aK6b = 0.f, aK6c = 0.f, aK6d = 0.f, aK6e = 0.f;

    float4 PE0a, PE1a, PE2a, PE0b, PE1b, PE2b, PE0c, PE1c, PE2c;
    float Ya, X0a, X1a, X2a, Yb, X0b, X1b, X2b, Yc, X0c, X1c, X2c;
    unsigned ABa, ABb, ABc; unsigned short Cwa, Cwb, Cwc;
    uint2 DGa, DGb, DGc;

    ISSUE_E(a, 0)
    ISSUE_E(b, 1)
    ISSUE_E(c, 2)
    ISSUE_V(a, 0)
    ISSUE_V(b, 1)

    int i = 0;
    while (i < cnt) {
      ISSUE_V(c, i + 2)
      COMPUTE(a)
      ISSUE_E(a, i + 3)
      ++i; if (i >= cnt) break;
      ISSUE_V(a, i + 2)
      COMPUTE(b)
      ISSUE_E(b, i + 3)
      ++i; if (i >= cnt) break;
      ISSUE_V(b, i + 2)
      COMPUTE(c)
      ISSUE_E(c, i + 3)
      ++i;
    }

    // epilogue: distributed accs -> wave-private m (LDS) -> lin2 + combine
    LWAIT;  // previous node's lin2 LDS reads drained before overwrite
    R[lane]            = aK0  * QDEG;
    R[96 + 3 * lane]   = aK2x * QDEG;
    R[97 + 3 * lane]   = aK2y * QDEG;
    R[98 + 3 * lane]   = aK2z * QDEG;
    R[480 + 5 * lane]  = aK5a * QDEG;
    R[481 + 5 * lane]  = aK5b * QDEG;
    R[482 + 5 * lane]  = aK5c * QDEG;
    R[483 + 5 * lane]  = aK5d * QDEG;
    R[484 + 5 * lane]  = aK5e * QDEG;
    if (lane < 32) {
      R[64 + lane]       = aK1  * QDEG;
      R[288 + 3 * lane]  = aK3x * QDEG;
      R[289 + 3 * lane]  = aK3y * QDEG;
      R[290 + 3 * lane]  = aK3z * QDEG;
      R[384 + 3 * lane]  = aK4x * QDEG;
      R[385 + 3 * lane]  = aK4y * QDEG;
      R[386 + 3 * lane]  = aK4z * QDEG;
      R[800 + 5 * lane]  = aK6a * QDEG;
      R[801 + 5 * lane]  = aK6b * QDEG;
      R[802 + 5 * lane]  = aK6c * QDEG;
      R[803 + 5 * lane]  = aK6d * QDEG;
      R[804 + 5 * lane]  = aK6e * QDEG;
    }
    LWAIT;
    float a = attr[n];
    const float* srow = s + (size_t)n * 160;
    float* orow = out + (size_t)n * 320;
    #pragma unroll
    for (int jo = 0; jo < 5; ++jo) {
      int oc = lane + 64 * jo;
      orow[oc] = lin2_col(R, w0, w1, w2, srow, a, oc);
    }
  }
#undef ISSUE_E
#undef ISSUE_V
#undef COMPUTE
#undef LWAIT
}

extern "C" void kernel_launch(void* const* d_in, const int* in_sizes, int n_in,
                              void* d_out, int out_size, void* d_ws, size_t ws_size,
                              hipStream_t stream) {
  const float* node_input = (const float*)d_in[0];
  const float* node_attr  = (const float*)d_in[1];
  const int*   edge_src   = (const int*)d_in[2];
  const int*   edge_dst   = (const int*)d_in[3];
  const float* edge_attr  = (const float*)d_in[4];
  const float* ele        = (const float*)d_in[5];
  const float* sc_w0      = (const float*)d_in[6];
  const float* sc_w1      = (const float*)d_in[7];
  const float* l1_w0      = (const float*)d_in[8];
  const float* l1_w1      = (const float*)d_in[9];
  const float* fc_w0      = (const float*)d_in[10];
  const float* fc_w1      = (const float*)d_in[11];
  const float* l2_w0      = (const float*)d_in[12];
  const float* l2_w1      = (const float*)d_in[13];
  const float* l2_w2      = (const float*)d_in[14];
  float* out = (float*)d_out;

  char* base = (char*)d_ws;
  float* y              = (float*)(base);                       // 6.40 MB
  float* s              = (float*)(base + 6400000);             // 6.40 MB
  unsigned short* wbuf  = (unsigned short*)(base + 12800000);   // 102.4 MB packed
  float* ed2            = (float*)(base + 115200000);           // 10.24 MB (SH+src, stride 16)
  int* sorted           = (int*)(base + 125440000);             // 0.64 MB
  int* counts           = (int*)(base + 126080000);
  int* offs             = (int*)(base + 126120960);
  int* cur              = (int*)(base + 126161920);
  int* order            = (int*)(base + 126202880);
  int* obeg             = (int*)(base + 126243840);
  int* ocnt             = (int*)(base + 126284800);
  int* dcur             = (int*)(base + 126325760);             // 1 KB
  unsigned short* fc1p  = (unsigned short*)(base + 126326784);  // 40 KB

  hipLaunchKernelGGL(k_init, dim3(80), dim3(256), 0, stream, counts, fc_w1, fc1p);
  hipLaunchKernelGGL(k_hist, dim3((N_EDGES + 255) / 256), dim3(256), 0, stream,
                     edge_dst, counts);
  hipLaunchKernelGGL(k_scan, dim3(1), dim3(256), 0, stream, counts, offs, cur, dcur);
  hipLaunchKernelGGL(k_scatter, dim3((N_EDGES + 255) / 256), dim3(256), 0, stream,
                     edge_dst, cur, sorted, counts, offs, dcur, order, obeg, ocnt);
  hipLaunchKernelGGL(node_pre, dim3(N_NODES * 160 / 256), dim3(256), 0, stream,
                     node_input, node_attr, sc_w0, sc_w1, l1_w0, l1_w1, s, y);
  hipLaunchKernelGGL(w_gemm, dim3(N_EDGES / 64), dim3(256), 0, stream,
                     ele, fc_w0, sorted, edge_src, edge_attr, fc1p, wbuf, ed2);
  hipLaunchKernelGGL(node_agg, dim3(NWAVES / 4), dim3(256), 0, stream,
                     y, s, node_attr, ed2, wbuf,
                     order, obeg, ocnt, l2_w0, l2_w1, l2_w2, out);
}

// Round 10
// 364.743 us; speedup vs baseline: 1.0780x; 1.0780x over previous
//
#include <hip/hip_runtime.h>
#include <cstddef>
#include <cstdint>

#define N_NODES 10000
#define N_EDGES 160000
#define NWAVES  8192   // node_agg: 2048 blocks x 4 waves, persistent; snake over ranks

// ---- constants ----
#define RS8    0.35355339059327373f   // 1/sqrt(8)
#define RS32   0.17677669529663687f   // 1/sqrt(32)
#define RS96   0.10206207261596575f   // 1/sqrt(96)
#define RS128  0.08838834764831845f   // 1/sqrt(128)
#define RS3    0.5773502691896258f    // 1/sqrt(3)
#define SQ3_   1.7320508075688772f
#define SQ5_   2.23606797749979f
#define A_     0.18257418583505536f   // 1/sqrt(30)
#define B_     0.31622776601683794f   // 1/sqrt(10)
#define SILU_C_ 1.6765208f
#define CS_    0.3826834323650898f    // sin(pi/8)
#define CX_    0.9238795325112867f    // cos(pi/8)
#define QDEG   0.25f                  // 1/sqrt(16)

typedef __attribute__((ext_vector_type(8))) short bf16x8;
typedef __attribute__((ext_vector_type(4))) float f32x4;

__device__ inline float bf2f(unsigned v) {
  union { unsigned u; float f; } c; c.u = v << 16; return c.f;
}
__device__ inline float bfhi(unsigned v) {   // float from HIGH 16 bits
  union { unsigned u; float f; } c; c.u = v & 0xffff0000u; return c.f;
}
__device__ inline unsigned short f2bf(float f) {
  union { float f; unsigned u; } c; c.f = f;
  unsigned r = c.u + 0x7fff + ((c.u >> 16) & 1);
  return (unsigned short)(r >> 16);
}
__device__ inline unsigned pack2bf(float a, float b) {
  return (unsigned)f2bf(a) | ((unsigned)f2bf(b) << 16);
}

// zero counts + build fc1p (fc1 64x320 f32 -> bf16 MFMA B-fragment order)
__global__ void k_init(int* __restrict__ counts, const float* __restrict__ fc1,
                       unsigned short* __restrict__ fc1p) {
  int i = blockIdx.x * blockDim.x + threadIdx.x;
  if (i < N_NODES) counts[i] = 0;
  if (i < 20480) {
    int j = i & 7, q = (i >> 3) & 3, n = (i >> 5) & 15, kq = (i >> 9) & 1, t = i >> 10;
    int k = kq * 32 + q * 8 + j;
    fc1p[i] = f2bf(fc1[k * 320 + t * 16 + n]);
  }
}

__global__ void k_hist(const int* __restrict__ edst, int* __restrict__ counts) {
  int e = blockIdx.x * blockDim.x + threadIdx.x;
  if (e < N_EDGES) atomicAdd(&counts[edst[e]], 1);
}

// exclusive scan of counts -> offs/cur; degree histogram + descending-degree
// exclusive scan -> dcur (single block).
__global__ __launch_bounds__(256) void k_scan(const int* __restrict__ counts,
                                              int* __restrict__ offs,
                                              int* __restrict__ cur,
                                              int* __restrict__ dcur) {
  __shared__ int ps[256];
  __shared__ int dbin[256];
  int t = threadIdx.x;
  dbin[t] = 0;
  int base = t * 40;
  int sum = 0;
  for (int i = 0; i < 40; ++i) {
    int idx = base + i;
    if (idx < N_NODES) sum += counts[idx];
  }
  ps[t] = sum;
  __syncthreads();
  for (int off = 1; off < 256; off <<= 1) {
    int v = (t >= off) ? ps[t - off] : 0;
    __syncthreads();
    ps[t] += v;
    __syncthreads();
  }
  int run = (t == 0) ? 0 : ps[t - 1];
  for (int i = 0; i < 40; ++i) {
    int idx = base + i;
    if (idx < N_NODES) {
      int c = counts[idx];
      offs[idx] = run; cur[idx] = run;
      run += c;
      atomicAdd(&dbin[c < 255 ? c : 255], 1);
    }
  }
  __syncthreads();
  int rb = 255 - t;
  int v = dbin[rb];
  __syncthreads();
  ps[t] = v;
  __syncthreads();
  for (int off = 1; off < 256; off <<= 1) {
    int u = (t >= off) ? ps[t - off] : 0;
    __syncthreads();
    ps[t] += u;
    __syncthreads();
  }
  dcur[rb] = ps[t] - v;
}

// edge scatter (sorted-by-dst) + node scatter (descending-degree rank order)
__global__ void k_scatter(const int* __restrict__ edst, int* __restrict__ cur,
                          int* __restrict__ sorted, const int* __restrict__ counts,
                          const int* __restrict__ offs,
                          int* __restrict__ dcur, int* __restrict__ order,
                          int* __restrict__ obeg, int* __restrict__ ocnt) {
  int e = blockIdx.x * blockDim.x + threadIdx.x;
  if (e < N_EDGES) {
    int d = edst[e];
    int p = atomicAdd(&cur[d], 1);
    sorted[p] = e;
  }
  if (e < N_NODES) {
    int c = counts[e];
    int b = c < 255 ? c : 255;
    int p = atomicAdd(&dcur[b], 1);
    order[p] = e; obeg[p] = offs[e]; ocnt[p] = c;
  }
}

struct WgemmShared {
  int ids[64];
  __align__(16) float ele[64][8];
  __align__(16) float ed[64 * 12];
  __align__(16) unsigned short h[64 * 72];   // 72-stride pad
};

__device__ inline f32x4 wtile(const unsigned short* __restrict__ fc1p,
                              bf16x8 a0, bf16x8 a1, int mrow, int quad, int t) {
  f32x4 acc = {0.f, 0.f, 0.f, 0.f};
  bf16x8 b0 = *(const bf16x8*)(fc1p + ((size_t)((t * 2 + 0) * 16 + mrow) * 4 + quad) * 8);
  bf16x8 b1 = *(const bf16x8*)(fc1p + ((size_t)((t * 2 + 1) * 16 + mrow) * 4 + quad) * 8);
  acc = __builtin_amdgcn_mfma_f32_16x16x32_bf16(b0, a0, acc, 0, 0, 0);
  acc = __builtin_amdgcn_mfma_f32_16x16x32_bf16(b1, a1, acc, 0, 0, 0);
  return acc;
}

// MFMA bf16 radial GEMM over 64 SORTED edges per block.
// wbuf PACKED per edge (640 B): [0,256) AB interleaved; [256,384) C;
// [384,640) DEFG interleaved (8B per k). ed2 stride 16 floats: SH + src@9.
__device__ void w_gemm_body(WgemmShared& sh, int blk,
    const float* __restrict__ ele, const float* __restrict__ fc0,
    const int* __restrict__ sorted, const int* __restrict__ esrc,
    const float* __restrict__ eattr, const unsigned short* __restrict__ fc1p,
    unsigned short* __restrict__ wout, float* __restrict__ ed2) {
  int t = threadIdx.x;
  int eb = blk * 64;

  if (t < 64) sh.ids[t] = sorted[eb + t];
  __syncthreads();
  if (t < 128) {
    int e = t >> 1, hh = t & 1;
    ((float4*)&sh.ele[e][0])[hh] = ((const float4*)(ele + (size_t)sh.ids[e] * 8))[hh];
  }
  for (int i = t; i < 576; i += 256) {
    int e = i / 9, k = i - e * 9;
    sh.ed[e * 12 + k] = eattr[(size_t)sh.ids[e] * 9 + k];
  }
  if (t < 64) {
    ((int*)sh.ed)[t * 12 + 9] = esrc[sh.ids[t]];
    sh.ed[t * 12 + 10] = 0.f; sh.ed[t * 12 + 11] = 0.f;
  }
  __syncthreads();
  // ed2 write: 3 float4 per edge (stride 16 floats; slots 12..15 unused)
  if (t < 192) {
    int e = t / 3, q = t - e * 3;
    ((float4*)(ed2 + (size_t)(eb + e) * 16))[q] = ((const float4*)(sh.ed + e * 12))[q];
  }
  // h = silu(ele@fc0/sqrt8)*SILU_C -> bf16, A-layout [edge][k], stride 72
  #pragma unroll
  for (int ii = 0; ii < 16; ++ii) {
    int idx = t + ii * 256;
    int e = idx >> 6, k = idx & 63;
    float acc = 0.f;
    #pragma unroll
    for (int m = 0; m < 8; ++m) acc += sh.ele[e][m] * fc0[m * 64 + k];
    acc *= RS8;
    float hv = SILU_C_ * acc / (1.f + __expf(-acc));
    sh.h[e * 72 + k] = f2bf(hv);
  }
  __syncthreads();

  int wv = t >> 6, lane = t & 63;
  int m0 = wv * 16;
  int mrow = lane & 15, quad = lane >> 4;
  bf16x8 a0 = *(const bf16x8*)(sh.h + (m0 + mrow) * 72 + quad * 8);
  bf16x8 a1 = *(const bf16x8*)(sh.h + (m0 + mrow) * 72 + 32 + quad * 8);
  char* wbase = (char*)wout + (size_t)(eb + m0 + mrow) * 640;
  const float K = 0.125f;
  #pragma unroll
  for (int tt = 0; tt < 4; ++tt) {
    f32x4 Av = wtile(fc1p, a0, a1, mrow, quad, tt);
    f32x4 Bv = wtile(fc1p, a0, a1, mrow, quad, tt + 4);
    uint4 st;
    st.x = pack2bf(Av[0] * K, Bv[0] * K);
    st.y = pack2bf(Av[1] * K, Bv[1] * K);
    st.z = pack2bf(Av[2] * K, Bv[2] * K);
    st.w = pack2bf(Av[3] * K, Bv[3] * K);
    *(uint4*)(wbase + 64 * tt + 16 * quad) = st;
  }
  #pragma unroll
  for (int tt = 8; tt < 12; ++tt) {
    f32x4 Cv = wtile(fc1p, a0, a1, mrow, quad, tt);
    uint2 st;
    st.x = pack2bf(Cv[0] * K, Cv[1] * K);
    st.y = pack2bf(Cv[2] * K, Cv[3] * K);
    *(uint2*)(wbase + 256 + 32 * (tt - 8) + 8 * quad) = st;
  }
  #pragma unroll
  for (int tt = 12; tt < 14; ++tt) {
    f32x4 Dv = wtile(fc1p, a0, a1, mrow, quad, tt);
    f32x4 Ev = wtile(fc1p, a0, a1, mrow, quad, tt + 2);
    f32x4 Fv = wtile(fc1p, a0, a1, mrow, quad, tt + 4);
    f32x4 Gv = wtile(fc1p, a0, a1, mrow, quad, tt + 6);
    char* db = wbase + 384 + 128 * (tt - 12) + 32 * quad;
    uint4 s0, s1;
    s0.x = pack2bf(Dv[0] * K, Ev[0] * K); s0.y = pack2bf(Fv[0] * K, Gv[0] * K);
    s0.z = pack2bf(Dv[1] * K, Ev[1] * K); s0.w = pack2bf(Fv[1] * K, Gv[1] * K);
    s1.x = pack2bf(Dv[2] * K, Ev[2] * K); s1.y = pack2bf(Fv[2] * K, Gv[2] * K);
    s1.z = pack2bf(Dv[3] * K, Ev[3] * K); s1.w = pack2bf(Fv[3] * K, Gv[3] * K);
    *(uint4*)(db) = s0;
    *(uint4*)(db + 16) = s1;
  }
}

// s[n][0:160]; y PADDED (stride 192 f): [0,64) scalar, then u'-th vector
// channel as float4 {x0,x1,x2,0} at 64+4u'.
__device__ void node_pre_body(int blk,
    const float* __restrict__ xin, const float* __restrict__ attr,
    const float* __restrict__ sc_w0, const float* __restrict__ sc_w1,
    const float* __restrict__ l1_w0, const float* __restrict__ l1_w1,
    float* __restrict__ s, float* __restrict__ y) {
  int idx = blk * 256 + threadIdx.x;
  int n = idx / 160, c = idx - n * 160;
  const float* xr = xin + (size_t)n * 160;
  float a = attr[n];
  if (c < 64) {
    float s_ = 0.f, y_ = 0.f;
    #pragma unroll 8
    for (int u = 0; u < 64; ++u) {
      float x = xr[u];
      s_ += x * sc_w0[u * 64 + c];
      y_ += x * l1_w0[u * 64 + c];
    }
    s[(size_t)n * 160 + c] = s_ * a * 0.125f;
    y[(size_t)n * 192 + c] = y_ * a * 0.125f;
  } else {
    int t = c - 64; int v = t / 3, i = t - v * 3;
    float s_ = 0.f, y_ = 0.f;
    #pragma unroll 8
    for (int u = 0; u < 32; ++u) {
      float x = xr[64 + u * 3 + i];
      s_ += x * sc_w1[u * 32 + v];
      y_ += x * l1_w1[u * 32 + v];
    }
    s[(size_t)n * 160 + c] = s_ * a * RS32;
    y[(size_t)n * 192 + 64 + v * 4 + i] = y_ * a * RS32;
    if (i == 2) y[(size_t)n * 192 + 64 + v * 4 + 3] = 0.f;
  }
}

// fused mid-stage: blocks [0,2500) = w_gemm, [2500,8750) = node_pre
__global__ __launch_bounds__(256) void k_mid(
    const float* __restrict__ ele, const float* __restrict__ fc0,
    const int* __restrict__ sorted, const int* __restrict__ esrc,
    const float* __restrict__ eattr, const unsigned short* __restrict__ fc1p,
    unsigned short* __restrict__ wout, float* __restrict__ ed2,
    const float* __restrict__ xin, const float* __restrict__ attr,
    const float* __restrict__ sc_w0, const float* __restrict__ sc_w1,
    const float* __restrict__ l1_w0, const float* __restrict__ l1_w1,
    float* __restrict__ s, float* __restrict__ y) {
  __shared__ WgemmShared sh;
  if (blockIdx.x < 2500) {
    w_gemm_body(sh, blockIdx.x, ele, fc0, sorted, esrc, eattr, fc1p, wout, ed2);
  } else {
    node_pre_body(blockIdx.x - 2500, xin, attr, sc_w0, sc_w1, l1_w0, l1_w1, s, y);
  }
}

__device__ inline float lin2_col(const float* __restrict__ sm,
                                 const float* __restrict__ w0,
                                 const float* __restrict__ w1,
                                 const float* __restrict__ w2,
                                 const float* __restrict__ srow,
                                 float a, int oc) {
  if (oc < 64) {
    float o = 0.f;
    #pragma unroll 8
    for (int u = 0; u < 96; ++u) o += sm[u] * w0[u * 64 + oc];
    return CS_ * srow[oc] + CX_ * (o * a * RS96);
  } else if (oc < 160) {
    int t = oc - 64, v = t / 3, i = t - v * 3;
    float o = 0.f;
    #pragma unroll 8
    for (int u = 0; u < 128; ++u) o += sm[96 + u * 3 + i] * w1[u * 32 + v];
    return CS_ * srow[oc] + CX_ * (o * a * RS128);
  } else {
    int t = oc - 160, v = t / 5, k = t - v * 5;
    float o = 0.f;
    #pragma unroll 8
    for (int u = 0; u < 96; ++u) o += sm[480 + u * 5 + k] * w2[u * 32 + v];
    return o * a * RS96;
  }
}

// PERSISTENT node_agg: 2048 blocks x 4 waves; wave gw processes degree-ranks
// {gw, 16383-gw} (snake pairing: biggest+smallest -> balanced, no drain tail).
// Two-slot pipeline: E-loads (SH+src) at distance 2, V-loads (y/w) at
// distance 1. Direct global->lane loads, fixed per-lane offsets, no LDS in
// the loop. Plain __launch_bounds__ (r7 lesson: don't cap the allocator).
#define WREG 960
__global__ __launch_bounds__(256) void node_agg(
    const float* __restrict__ y, const float* __restrict__ s,
    const float* __restrict__ attr, const float* __restrict__ ed2,
    const unsigned short* __restrict__ wbuf,
    const int* __restrict__ order, const int* __restrict__ obeg,
    const int* __restrict__ ocnt,
    const float* __restrict__ w0, const float* __restrict__ w1,
    const float* __restrict__ w2, float* __restrict__ out) {
  __shared__ __align__(16) float smem[4 * WREG];
  int tid = threadIdx.x, wid = tid >> 6, lane = tid & 63, l31 = lane & 31;
  float* R = smem + wid * WREG;
  int gw = blockIdx.x * 4 + wid;
  // fixed per-lane byte offsets (loop-invariant)
  int voY  = 4 * lane;           // y scalar block
  int voX  = 256 + 16 * l31;     // y vector float4 {x0,x1,x2,0}
  int voAB = 4 * lane;           // wbuf AB
  int voC  = 256 + 2 * lane;     // wbuf C
  int voDG = 384 + 8 * l31;      // wbuf DEFG

#define E_LOAD(S, idx)                                                         \
  if ((idx) < cnt) {                                                           \
    const float4* ep = (const float4*)(ed2 + (size_t)(beg + (idx)) * 16);      \
    PE0##S = ep[0]; PE1##S = ep[1]; PE2##S = ep[2];                            \
  }
#define V_LOAD(S, idx)                                                         \
  if ((idx) < cnt) {                                                           \
    int srcn = __float_as_int(PE2##S.y);                                       \
    const char* yb = (const char*)y + (size_t)srcn * 768;                      \
    Y##S = *(const float*)(yb + voY);                                          \
    X##S = *(const f32x4*)(yb + voX);                                          \
    const char* wb = (const char*)wbuf + (size_t)(beg + (idx)) * 640;          \
    AB##S = *(const unsigned*)(wb + voAB);                                     \
    Cw##S = *(const unsigned short*)(wb + voC);                                \
    DG##S = *(const uint2*)(wb + voDG);                                        \
  }
#define COMPUTE(S)                                                             \
  {                                                                            \
    float e0 = PE0##S.x, ey = PE0##S.y, ez = PE0##S.z, ex = PE0##S.w;          \
    float q0 = PE1##S.x, q1 = PE1##S.y, q2 = PE1##S.z, q3 = PE1##S.w;          \
    float q4 = PE2##S.x;                                                       \
    float Yv = Y##S, x0 = X##S.x, x1 = X##S.y, x2 = X##S.z;                    \
    float vA = bf2f(AB##S), vB = bfhi(AB##S), vC = bf2f(Cw##S);                \
    float vD = bf2f(DG##S.x), vE = bfhi(DG##S.x);                              \
    float vF = bf2f(DG##S.y), vG = bfhi(DG##S.y);                              \
    aK0 += Yv * e0 * vA;                                                       \
    float tB = Yv * vB; aK2x += tB * ey; aK2y += tB * ez; aK2z += tB * ex;     \
    float tC = Yv * vC;                                                        \
    aK5a += tC * q0; aK5b += tC * q1; aK5c += tC * q2;                         \
    aK5d += tC * q3; aK5e += tC * q4;                                          \
    float t1 = x0 * ey + x1 * ez + x2 * ex; aK1 += (RS3 * vE) * t1;            \
    float s3 = e0 * vD; aK3x += x0 * s3; aK3y += x1 * s3; aK3z += x2 * s3;     \
    float s4 = SQ3_ * vG;                                                      \
    aK4x += s4 * (B_ * (x2 * q0 + x1 * q1 - x0 * q4) - A_ * x0 * q2);          \
    aK4y += s4 * (B_ * (x0 * q1 + x2 * q3) + 2.f * A_ * x1 * q2);              \
    aK4z += s4 * (B_ * (x0 * q0 + x1 * q3 + x2 * q4) - A_ * x2 * q2);          \
    float s6 = SQ5_ * vF;                                                      \
    aK6a += s6 * (-B_ * (x0 * ex + x2 * ey));                                  \
    aK6b += s6 * (-B_ * (x0 * ez + x1 * ey));                                  \
    aK6c += s6 * ( A_ * (x0 * ey + x2 * ex - 2.f * x1 * ez));                  \
    aK6d += s6 * (-B_ * (x1 * ex + x2 * ez));                                  \
    aK6e += s6 * ( B_ * (x0 * ey - x2 * ex));                                  \
  }
#define LWAIT __asm__ volatile("s_waitcnt lgkmcnt(0)" ::: "memory")

  for (int pass = 0; pass < 2; ++pass) {
    int rank = pass ? (16383 - gw) : gw;
    if (rank >= N_NODES) continue;
    int n = order[rank], beg = obeg[rank], cnt = ocnt[rank];

    float aK0 = 0.f, aK2x = 0.f, aK2y = 0.f, aK2z = 0.f;
    float aK5a = 0.f, aK5b = 0.f, aK5c = 0.f, aK5d = 0.f, aK5e = 0.f;
    float aK1 = 0.f, aK3x = 0.f, aK3y = 0.f, aK3z = 0.f;
    float aK4x = 0.f, aK4y = 0.f, aK4z = 0.f;
    float aK6a = 0.f, aK6b = 0.f, aK6c = 0.f, aK6d = 0.f, aK6e = 0.f;

    float4 PE0a, PE1a, PE2a, PE0b, PE1b, PE2b;
    float Ya, Yb; f32x4 Xa, Xb;
    unsigned ABa, ABb; unsigned short Cwa, Cwb;
    uint2 DGa, DGb;

    E_LOAD(a, 0)
    E_LOAD(b, 1)
    V_LOAD(a, 0)

    int i = 0;
    while (i < cnt) {
      V_LOAD(b, i + 1)
      COMPUTE(a)
      E_LOAD(a, i + 2)
      ++i; if (i >= cnt) break;
      V_LOAD(a, i + 1)
      COMPUTE(b)
      E_LOAD(b, i + 2)
      ++i;
    }

    // epilogue: distributed accs -> wave-private m (LDS) -> lin2 + combine
    LWAIT;  // previous node's lin2 LDS reads drained before overwrite
    R[lane]            = aK0  * QDEG;
    R[96 + 3 * lane]   = aK2x * QDEG;
    R[97 + 3 * lane]   = aK2y * QDEG;
    R[98 + 3 * lane]   = aK2z * QDEG;
    R[480 + 5 * lane]  = aK5a * QDEG;
    R[481 + 5 * lane]  = aK5b * QDEG;
    R[482 + 5 * lane]  = aK5c * QDEG;
    R[483 + 5 * lane]  = aK5d * QDEG;
    R[484 + 5 * lane]  = aK5e * QDEG;
    if (lane < 32) {
      R[64 + lane]       = aK1  * QDEG;
      R[288 + 3 * lane]  = aK3x * QDEG;
      R[289 + 3 * lane]  = aK3y * QDEG;
      R[290 + 3 * lane]  = aK3z * QDEG;
      R[384 + 3 * lane]  = aK4x * QDEG;
      R[385 + 3 * lane]  = aK4y * QDEG;
      R[386 + 3 * lane]  = aK4z * QDEG;
      R[800 + 5 * lane]  = aK6a * QDEG;
      R[801 + 5 * lane]  = aK6b * QDEG;
      R[802 + 5 * lane]  = aK6c * QDEG;
      R[803 + 5 * lane]  = aK6d * QDEG;
      R[804 + 5 * lane]  = aK6e * QDEG;
    }
    LWAIT;
    float a = attr[n];
    const float* srow = s + (size_t)n * 160;
    float* orow = out + (size_t)n * 320;
    #pragma unroll
    for (int jo = 0; jo < 5; ++jo) {
      int oc = lane + 64 * jo;
      orow[oc] = lin2_col(R, w0, w1, w2, srow, a, oc);
    }
  }
#undef E_LOAD
#undef V_LOAD
#undef COMPUTE
#undef LWAIT
}

extern "C" void kernel_launch(void* const* d_in, const int* in_sizes, int n_in,
                              void* d_out, int out_size, void* d_ws, size_t ws_size,
                              hipStream_t stream) {
  const float* node_input = (const float*)d_in[0];
  const float* node_attr  = (const float*)d_in[1];
  const int*   edge_src   = (const int*)d_in[2];
  const int*   edge_dst   = (const int*)d_in[3];
  const float* edge_attr  = (const float*)d_in[4];
  const float* ele        = (const float*)d_in[5];
  const float* sc_w0      = (const float*)d_in[6];
  const float* sc_w1      = (const float*)d_in[7];
  const float* l1_w0      = (const float*)d_in[8];
  const float* l1_w1      = (const float*)d_in[9];
  const float* fc_w0      = (const float*)d_in[10];
  const float* fc_w1      = (const float*)d_in[11];
  const float* l2_w0      = (const float*)d_in[12];
  const float* l2_w1      = (const float*)d_in[13];
  const float* l2_w2      = (const float*)d_in[14];
  float* out = (float*)d_out;

  char* base = (char*)d_ws;
  float* y              = (float*)(base);                       // 7.68 MB (padded, stride 192)
  float* s              = (float*)(base + 7680000);             // 6.40 MB
  unsigned short* wbuf  = (unsigned short*)(base + 14080000);   // 102.4 MB packed
  float* ed2            = (float*)(base + 116480000);           // 10.24 MB (SH+src, stride 16)
  int* sorted           = (int*)(base + 126720000);             // 0.64 MB
  int* counts           = (int*)(base + 127360000);
  int* offs             = (int*)(base + 127400960);
  int* cur              = (int*)(base + 127441920);
  int* order            = (int*)(base + 127482880);
  int* obeg             = (int*)(base + 127523840);
  int* ocnt             = (int*)(base + 127564800);
  int* dcur             = (int*)(base + 127605760);             // 1 KB
  unsigned short* fc1p  = (unsigned short*)(base + 127606784);  // 40 KB

  hipLaunchKernelGGL(k_init, dim3(80), dim3(256), 0, stream, counts, fc_w1, fc1p);
  hipLaunchKernelGGL(k_hist, dim3((N_EDGES + 255) / 256), dim3(256), 0, stream,
                     edge_dst, counts);
  hipLaunchKernelGGL(k_scan, dim3(1), dim3(256), 0, stream, counts, offs, cur, dcur);
  hipLaunchKernelGGL(k_scatter, dim3((N_EDGES + 255) / 256), dim3(256), 0, stream,
                     edge_dst, cur, sorted, counts, offs, dcur, order, obeg, ocnt);
  hipLaunchKernelGGL(k_mid, dim3(2500 + 6250), dim3(256), 0, stream,
                     ele, fc_w0, sorted, edge_src, edge_attr, fc1p, wbuf, ed2,
                     node_input, node_attr, sc_w0, sc_w1, l1_w0, l1_w1, s, y);
  hipLaunchKernelGGL(node_agg, dim3(NWAVES / 4), dim3(256), 0, stream,
                     y, s, node_attr, ed2, wbuf,
                     order, obeg, ocnt, l2_w0, l2_w1, l2_w2, out);
}

// Round 11
// 340.642 us; speedup vs baseline: 1.1543x; 1.0708x over previous
//
#include <hip/hip_runtime.h>
#include <cstddef>
#include <cstdint>

#define N_NODES 10000
#define N_EDGES 160000

// ---- constants ----
#define RS8    0.35355339059327373f   // 1/sqrt(8)
#define RS32   0.17677669529663687f   // 1/sqrt(32)
#define RS96   0.10206207261596575f   // 1/sqrt(96)
#define RS128  0.08838834764831845f   // 1/sqrt(128)
#define RS3    0.5773502691896258f    // 1/sqrt(3)
#define SQ3_   1.7320508075688772f
#define SQ5_   2.23606797749979f
#define A_     0.18257418583505536f   // 1/sqrt(30)
#define B_     0.31622776601683794f   // 1/sqrt(10)
#define SILU_C_ 1.6765208f
#define CS_    0.3826834323650898f    // sin(pi/8)
#define CX_    0.9238795325112867f    // cos(pi/8)
#define QDEG   0.25f                  // 1/sqrt(16)

typedef __attribute__((ext_vector_type(8))) short bf16x8;
typedef __attribute__((ext_vector_type(4))) float f32x4;

__device__ inline float bf2f(unsigned v) {
  union { unsigned u; float f; } c; c.u = v << 16; return c.f;
}
__device__ inline float bfhi(unsigned v) {   // float from HIGH 16 bits
  union { unsigned u; float f; } c; c.u = v & 0xffff0000u; return c.f;
}
__device__ inline unsigned short f2bf(float f) {
  union { float f; unsigned u; } c; c.f = f;
  unsigned r = c.u + 0x7fff + ((c.u >> 16) & 1);
  return (unsigned short)(r >> 16);
}
__device__ inline unsigned pack2bf(float a, float b) {
  return (unsigned)f2bf(a) | ((unsigned)f2bf(b) << 16);
}

// zero counts + build fc1p (fc1 64x320 f32 -> bf16 MFMA B-fragment order)
__global__ void k_init(int* __restrict__ counts, const float* __restrict__ fc1,
                       unsigned short* __restrict__ fc1p) {
  int i = blockIdx.x * blockDim.x + threadIdx.x;
  if (i < N_NODES) counts[i] = 0;
  if (i < 20480) {
    int j = i & 7, q = (i >> 3) & 3, n = (i >> 5) & 15, kq = (i >> 9) & 1, t = i >> 10;
    int k = kq * 32 + q * 8 + j;
    fc1p[i] = f2bf(fc1[k * 320 + t * 16 + n]);
  }
}

__global__ void k_hist(const int* __restrict__ edst, int* __restrict__ counts) {
  int e = blockIdx.x * blockDim.x + threadIdx.x;
  if (e < N_EDGES) atomicAdd(&counts[edst[e]], 1);
}

// exclusive scan of counts -> offs/cur; degree histogram + descending-degree
// exclusive scan -> dcur (single block).
__global__ __launch_bounds__(256) void k_scan(const int* __restrict__ counts,
                                              int* __restrict__ offs,
                                              int* __restrict__ cur,
                                              int* __restrict__ dcur) {
  __shared__ int ps[256];
  __shared__ int dbin[256];
  int t = threadIdx.x;
  dbin[t] = 0;
  int base = t * 40;
  int sum = 0;
  for (int i = 0; i < 40; ++i) {
    int idx = base + i;
    if (idx < N_NODES) sum += counts[idx];
  }
  ps[t] = sum;
  __syncthreads();
  for (int off = 1; off < 256; off <<= 1) {
    int v = (t >= off) ? ps[t - off] : 0;
    __syncthreads();
    ps[t] += v;
    __syncthreads();
  }
  int run = (t == 0) ? 0 : ps[t - 1];
  for (int i = 0; i < 40; ++i) {
    int idx = base + i;
    if (idx < N_NODES) {
      int c = counts[idx];
      offs[idx] = run; cur[idx] = run;
      run += c;
      atomicAdd(&dbin[c < 255 ? c : 255], 1);
    }
  }
  __syncthreads();
  int rb = 255 - t;
  int v = dbin[rb];
  __syncthreads();
  ps[t] = v;
  __syncthreads();
  for (int off = 1; off < 256; off <<= 1) {
    int u = (t >= off) ? ps[t - off] : 0;
    __syncthreads();
    ps[t] += u;
    __syncthreads();
  }
  dcur[rb] = ps[t] - v;
}

// Permute kernel: per edge compute sorted position p and SCATTER-WRITE the
// permuted per-edge stream ed2 (stride 20 f): [0..8]=SH, [9]=src,
// [10,11]=pad, [12..19]=ele row. Inputs staged coalesced in LDS. Also the
// node scatter (descending-degree rank -> order/obeg/ocnt).
__global__ __launch_bounds__(256) void k_perm(
    const int* __restrict__ edst, int* __restrict__ cur,
    const int* __restrict__ counts, const int* __restrict__ offs,
    int* __restrict__ dcur, int* __restrict__ order,
    int* __restrict__ obeg, int* __restrict__ ocnt,
    const float* __restrict__ ele, const float* __restrict__ eattr,
    const int* __restrict__ esrc, float* __restrict__ ed2) {
  __shared__ __align__(16) float sh_ea[256 * 9];
  __shared__ __align__(16) float sh_el[256 * 8];
  int t = threadIdx.x;
  int eb = blockIdx.x * 256;
  int e = eb + t;
  for (int i = t; i < 2304; i += 256) sh_ea[i] = eattr[(size_t)eb * 9 + i];
  {
    const float4* src = (const float4*)(ele + (size_t)eb * 8);
    float4* dst = (float4*)sh_el;
    dst[t] = src[t]; dst[t + 256] = src[t + 256];
  }
  __syncthreads();
  int d = edst[e];
  int p = atomicAdd(&cur[d], 1);
  const float* ea = sh_ea + t * 9;
  const float* el = sh_el + t * 8;
  float4 r0 = {ea[0], ea[1], ea[2], ea[3]};
  float4 r1 = {ea[4], ea[5], ea[6], ea[7]};
  float4 r2 = {ea[8], __int_as_float(esrc[e]), 0.f, 0.f};
  float4 r3 = {el[0], el[1], el[2], el[3]};
  float4 r4 = {el[4], el[5], el[6], el[7]};
  float4* dst = (float4*)(ed2 + (size_t)p * 20);
  dst[0] = r0; dst[1] = r1; dst[2] = r2; dst[3] = r3; dst[4] = r4;
  if (e < N_NODES) {
    int c = counts[e];
    int b = c < 255 ? c : 255;
    int q = atomicAdd(&dcur[b], 1);
    order[q] = e; obeg[q] = offs[e]; ocnt[q] = c;
  }
}

__device__ inline f32x4 wtile(const unsigned short* __restrict__ fc1p,
                              bf16x8 a0, bf16x8 a1, int mrow, int quad, int t) {
  f32x4 acc = {0.f, 0.f, 0.f, 0.f};
  bf16x8 b0 = *(const bf16x8*)(fc1p + ((size_t)((t * 2 + 0) * 16 + mrow) * 4 + quad) * 8);
  bf16x8 b1 = *(const bf16x8*)(fc1p + ((size_t)((t * 2 + 1) * 16 + mrow) * 4 + quad) * 8);
  acc = __builtin_amdgcn_mfma_f32_16x16x32_bf16(b0, a0, acc, 0, 0, 0);
  acc = __builtin_amdgcn_mfma_f32_16x16x32_bf16(b1, a1, acc, 0, 0, 0);
  return acc;
}

struct WgemmShared {
  __align__(16) float ele[64][8];
  __align__(16) unsigned short h[64 * 72];   // 72-stride pad
};

// STREAMING MFMA radial GEMM: 64 edges/block, reads ele slices from the
// already-permuted ed2 (sequential), writes packed wbuf (640 B/edge):
// [0,256) AB interleaved; [256,384) C; [384,640) DEFG interleaved.
__device__ void w_gemm_body(WgemmShared& sh, int blk,
    const float* __restrict__ ed2, const float* __restrict__ fc0,
    const unsigned short* __restrict__ fc1p, unsigned short* __restrict__ wout) {
  int t = threadIdx.x;
  int eb = blk * 64;
  if (t < 128) {
    int e = t >> 1, hh = t & 1;
    ((float4*)&sh.ele[e][0])[hh] =
        *(const float4*)(ed2 + (size_t)(eb + e) * 20 + 12 + hh * 4);
  }
  __syncthreads();
  #pragma unroll
  for (int ii = 0; ii < 16; ++ii) {
    int idx = t + ii * 256;
    int e = idx >> 6, k = idx & 63;
    float acc = 0.f;
    #pragma unroll
    for (int m = 0; m < 8; ++m) acc += sh.ele[e][m] * fc0[m * 64 + k];
    acc *= RS8;
    float hv = SILU_C_ * acc / (1.f + __expf(-acc));
    sh.h[e * 72 + k] = f2bf(hv);
  }
  __syncthreads();

  int wv = t >> 6, lane = t & 63;
  int m0 = wv * 16;
  int mrow = lane & 15, quad = lane >> 4;
  bf16x8 a0 = *(const bf16x8*)(sh.h + (m0 + mrow) * 72 + quad * 8);
  bf16x8 a1 = *(const bf16x8*)(sh.h + (m0 + mrow) * 72 + 32 + quad * 8);
  char* wbase = (char*)wout + (size_t)(eb + m0 + mrow) * 640;
  const float K = 0.125f;
  #pragma unroll
  for (int tt = 0; tt < 4; ++tt) {
    f32x4 Av = wtile(fc1p, a0, a1, mrow, quad, tt);
    f32x4 Bv = wtile(fc1p, a0, a1, mrow, quad, tt + 4);
    uint4 st;
    st.x = pack2bf(Av[0] * K, Bv[0] * K);
    st.y = pack2bf(Av[1] * K, Bv[1] * K);
    st.z = pack2bf(Av[2] * K, Bv[2] * K);
    st.w = pack2bf(Av[3] * K, Bv[3] * K);
    *(uint4*)(wbase + 64 * tt + 16 * quad) = st;
  }
  #pragma unroll
  for (int tt = 8; tt < 12; ++tt) {
    f32x4 Cv = wtile(fc1p, a0, a1, mrow, quad, tt);
    uint2 st;
    st.x = pack2bf(Cv[0] * K, Cv[1] * K);
    st.y = pack2bf(Cv[2] * K, Cv[3] * K);
    *(uint2*)(wbase + 256 + 32 * (tt - 8) + 8 * quad) = st;
  }
  #pragma unroll
  for (int tt = 12; tt < 14; ++tt) {
    f32x4 Dv = wtile(fc1p, a0, a1, mrow, quad, tt);
    f32x4 Ev = wtile(fc1p, a0, a1, mrow, quad, tt + 2);
    f32x4 Fv = wtile(fc1p, a0, a1, mrow, quad, tt + 4);
    f32x4 Gv = wtile(fc1p, a0, a1, mrow, quad, tt + 6);
    char* db = wbase + 384 + 128 * (tt - 12) + 32 * quad;
    uint4 s0, s1;
    s0.x = pack2bf(Dv[0] * K, Ev[0] * K); s0.y = pack2bf(Fv[0] * K, Gv[0] * K);
    s0.z = pack2bf(Dv[1] * K, Ev[1] * K); s0.w = pack2bf(Fv[1] * K, Gv[1] * K);
    s1.x = pack2bf(Dv[2] * K, Ev[2] * K); s1.y = pack2bf(Fv[2] * K, Gv[2] * K);
    s1.z = pack2bf(Dv[3] * K, Ev[3] * K); s1.w = pack2bf(Fv[3] * K, Gv[3] * K);
    *(uint4*)(db) = s0;
    *(uint4*)(db + 16) = s1;
  }
}

// y PADDED (stride 192 f): [0,64) scalar, vector channel u' as float4
// {x0,x1,x2,0} at 64+4u'. (s is computed in node_agg's epilogue now.)
__device__ void node_pre_body(int blk,
    const float* __restrict__ xin, const float* __restrict__ attr,
    const float* __restrict__ l1_w0, const float* __restrict__ l1_w1,
    float* __restrict__ y) {
  int idx = blk * 256 + threadIdx.x;
  int n = idx / 160, c = idx - n * 160;
  const float* xr = xin + (size_t)n * 160;
  float a = attr[n];
  if (c < 64) {
    float y_ = 0.f;
    #pragma unroll 8
    for (int u = 0; u < 64; ++u) y_ += xr[u] * l1_w0[u * 64 + c];
    y[(size_t)n * 192 + c] = y_ * a * 0.125f;
  } else {
    int t = c - 64; int v = t / 3, i = t - v * 3;
    float y_ = 0.f;
    #pragma unroll 8
    for (int u = 0; u < 32; ++u) y_ += xr[64 + u * 3 + i] * l1_w1[u * 32 + v];
    y[(size_t)n * 192 + 64 + v * 4 + i] = y_ * a * RS32;
    if (i == 2) y[(size_t)n * 192 + 64 + v * 4 + 3] = 0.f;
  }
}

// fused mid-stage: blocks [0,2500) = w_gemm, [2500,8750) = node_pre
__global__ __launch_bounds__(256) void k_mid(
    const float* __restrict__ ed2, const float* __restrict__ fc0,
    const unsigned short* __restrict__ fc1p, unsigned short* __restrict__ wout,
    const float* __restrict__ xin, const float* __restrict__ attr,
    const float* __restrict__ l1_w0, const float* __restrict__ l1_w1,
    float* __restrict__ y) {
  __shared__ WgemmShared sh;
  if (blockIdx.x < 2500) {
    w_gemm_body(sh, blockIdx.x, ed2, fc0, fc1p, wout);
  } else {
    node_pre_body(blockIdx.x - 2500, xin, attr, l1_w0, l1_w1, y);
  }
}

// node_agg: 2500 blocks x 4 waves, ONE NODE PER WAVE in degree-desc order
// (r6 dispatch — HW block scheduler balances better than static persistence).
// Direct global->lane loads, packed wbuf (3 loads), padded-y float4 X,
// E/V two-slot pipeline. lin1-s fused into the epilogue.
#define WREG 960
__global__ __launch_bounds__(256) void node_agg(
    const float* __restrict__ y, const float* __restrict__ xin,
    const float* __restrict__ attr, const float* __restrict__ ed2,
    const unsigned short* __restrict__ wbuf,
    const int* __restrict__ order, const int* __restrict__ obeg,
    const int* __restrict__ ocnt,
    const float* __restrict__ sc_w0, const float* __restrict__ sc_w1,
    const float* __restrict__ w0, const float* __restrict__ w1,
    const float* __restrict__ w2, float* __restrict__ out) {
  __shared__ __align__(16) float smem[4 * WREG];
  int tid = threadIdx.x, wid = tid >> 6, lane = tid & 63, l31 = lane & 31;
  float* R = smem + wid * WREG;
  int gw = blockIdx.x * 4 + wid;
  // fixed per-lane byte offsets (loop-invariant)
  int voY  = 4 * lane;           // y scalar block
  int voX  = 256 + 16 * l31;     // y vector float4 {x0,x1,x2,0}
  int voAB = 4 * lane;           // wbuf AB
  int voC  = 256 + 2 * lane;     // wbuf C
  int voDG = 384 + 8 * l31;      // wbuf DEFG

#define E_LOAD(S, idx)                                                         \
  if ((idx) < cnt) {                                                           \
    const float4* ep = (const float4*)(ed2 + (size_t)(beg + (idx)) * 20);      \
    PE0##S = ep[0]; PE1##S = ep[1]; PE2##S = ep[2];                            \
  }
#define V_LOAD(S, idx)                                                         \
  if ((idx) < cnt) {                                                           \
    int srcn = __float_as_int(PE2##S.y);                                       \
    const char* yb = (const char*)y + (size_t)srcn * 768;                      \
    Y##S = *(const float*)(yb + voY);                                          \
    X##S = *(const f32x4*)(yb + voX);                                          \
    const char* wb = (const char*)wbuf + (size_t)(beg + (idx)) * 640;          \
    AB##S = *(const unsigned*)(wb + voAB);                                     \
    Cw##S = *(const unsigned short*)(wb + voC);                                \
    DG##S = *(const uint2*)(wb + voDG);                                        \
  }
#define COMPUTE(S)                                                             \
  {                                                                            \
    float e0 = PE0##S.x, ey = PE0##S.y, ez = PE0##S.z, ex = PE0##S.w;          \
    float q0 = PE1##S.x, q1 = PE1##S.y, q2 = PE1##S.z, q3 = PE1##S.w;          \
    float q4 = PE2##S.x;                                                       \
    float Yv = Y##S, x0 = X##S.x, x1 = X##S.y, x2 = X##S.z;                    \
    float vA = bf2f(AB##S), vB = bfhi(AB##S), vC = bf2f(Cw##S);                \
    float vD = bf2f(DG##S.x), vE = bfhi(DG##S.x);                              \
    float vF = bf2f(DG##S.y), vG = bfhi(DG##S.y);                              \
    aK0 += Yv * e0 * vA;                                                       \
    float tB = Yv * vB; aK2x += tB * ey; aK2y += tB * ez; aK2z += tB * ex;     \
    float tC = Yv * vC;                                                        \
    aK5a += tC * q0; aK5b += tC * q1; aK5c += tC * q2;                         \
    aK5d += tC * q3; aK5e += tC * q4;                                          \
    float t1 = x0 * ey + x1 * ez + x2 * ex; aK1 += (RS3 * vE) * t1;            \
    float s3 = e0 * vD; aK3x += x0 * s3; aK3y += x1 * s3; aK3z += x2 * s3;     \
    float s4 = SQ3_ * vG;                                                      \
    aK4x += s4 * (B_ * (x2 * q0 + x1 * q1 - x0 * q4) - A_ * x0 * q2);          \
    aK4y += s4 * (B_ * (x0 * q1 + x2 * q3) + 2.f * A_ * x1 * q2);              \
    aK4z += s4 * (B_ * (x0 * q0 + x1 * q3 + x2 * q4) - A_ * x2 * q2);          \
    float s6 = SQ5_ * vF;                                                      \
    aK6a += s6 * (-B_ * (x0 * ex + x2 * ey));                                  \
    aK6b += s6 * (-B_ * (x0 * ez + x1 * ey));                                  \
    aK6c += s6 * ( A_ * (x0 * ey + x2 * ex - 2.f * x1 * ez));                  \
    aK6d += s6 * (-B_ * (x1 * ex + x2 * ez));                                  \
    aK6e += s6 * ( B_ * (x0 * ey - x2 * ex));                                  \
  }
#define LWAIT __asm__ volatile("s_waitcnt lgkmcnt(0)" ::: "memory")

  int n = order[gw], beg = obeg[gw], cnt = ocnt[gw];

  float aK0 = 0.f, aK2x = 0.f, aK2y = 0.f, aK2z = 0.f;
  float aK5a = 0.f, aK5b = 0.f, aK5c = 0.f, aK5d = 0.f, aK5e = 0.f;
  float aK1 = 0.f, aK3x = 0.f, aK3y = 0.f, aK3z = 0.f;
  float aK4x = 0.f, aK4y = 0.f, aK4z = 0.f;
  float aK6a = 0.f, aK6b = 0.f, aK6c = 0.f, aK6d = 0.f, aK6e = 0.f;

  float4 PE0a, PE1a, PE2a, PE0b, PE1b, PE2b;
  float Ya, Yb; f32x4 Xa, Xb;
  unsigned ABa, ABb; unsigned short Cwa, Cwb;
  uint2 DGa, DGb;

  E_LOAD(a, 0)
  E_LOAD(b, 1)
  V_LOAD(a, 0)

  int i = 0;
  while (i < cnt) {
    V_LOAD(b, i + 1)
    COMPUTE(a)
    E_LOAD(a, i + 2)
    ++i; if (i >= cnt) break;
    V_LOAD(a, i + 1)
    COMPUTE(b)
    E_LOAD(b, i + 2)
    ++i;
  }

  // epilogue: accs -> wave-private m (LDS) -> lin2 + fused lin1-s + combine
  R[lane]            = aK0  * QDEG;
  R[96 + 3 * lane]   = aK2x * QDEG;
  R[97 + 3 * lane]   = aK2y * QDEG;
  R[98 + 3 * lane]   = aK2z * QDEG;
  R[480 + 5 * lane]  = aK5a * QDEG;
  R[481 + 5 * lane]  = aK5b * QDEG;
  R[482 + 5 * lane]  = aK5c * QDEG;
  R[483 + 5 * lane]  = aK5d * QDEG;
  R[484 + 5 * lane]  = aK5e * QDEG;
  if (lane < 32) {
    R[64 + lane]       = aK1  * QDEG;
    R[288 + 3 * lane]  = aK3x * QDEG;
    R[289 + 3 * lane]  = aK3y * QDEG;
    R[290 + 3 * lane]  = aK3z * QDEG;
    R[384 + 3 * lane]  = aK4x * QDEG;
    R[385 + 3 * lane]  = aK4y * QDEG;
    R[386 + 3 * lane]  = aK4z * QDEG;
    R[800 + 5 * lane]  = aK6a * QDEG;
    R[801 + 5 * lane]  = aK6b * QDEG;
    R[802 + 5 * lane]  = aK6c * QDEG;
    R[803 + 5 * lane]  = aK6d * QDEG;
    R[804 + 5 * lane]  = aK6e * QDEG;
  }
  LWAIT;
  float a = attr[n];
  const float* xr = xin + (size_t)n * 160;
  float* orow = out + (size_t)n * 320;
  #pragma unroll
  for (int jo = 0; jo < 5; ++jo) {
    int oc = lane + 64 * jo;
    float res;
    if (oc < 64) {
      float o = 0.f, sv = 0.f;
      #pragma unroll 8
      for (int u = 0; u < 96; ++u) o += R[u] * w0[u * 64 + oc];
      #pragma unroll 8
      for (int u = 0; u < 64; ++u) sv += xr[u] * sc_w0[u * 64 + oc];
      res = CS_ * (sv * a * 0.125f) + CX_ * (o * a * RS96);
    } else if (oc < 160) {
      int t2 = oc - 64, v = t2 / 3, ii = t2 - v * 3;
      float o = 0.f, sv = 0.f;
      #pragma unroll 8
      for (int u = 0; u < 128; ++u) o += R[96 + u * 3 + ii] * w1[u * 32 + v];
      #pragma unroll 8
      for (int u = 0; u < 32; ++u) sv += xr[64 + u * 3 + ii] * sc_w1[u * 32 + v];
      res = CS_ * (sv * a * RS32) + CX_ * (o * a * RS128);
    } else {
      int t2 = oc - 160, v = t2 / 5, kk = t2 - v * 5;
      float o = 0.f;
      #pragma unroll 8
      for (int u = 0; u < 96; ++u) o += R[480 + u * 5 + kk] * w2[u * 32 + v];
      res = o * a * RS96;
    }
    orow[oc] = res;
  }
#undef E_LOAD
#undef V_LOAD
#undef COMPUTE
#undef LWAIT
}

extern "C" void kernel_launch(void* const* d_in, const int* in_sizes, int n_in,
                              void* d_out, int out_size, void* d_ws, size_t ws_size,
                              hipStream_t stream) {
  const float* node_input = (const float*)d_in[0];
  const float* node_attr  = (const float*)d_in[1];
  const int*   edge_src   = (const int*)d_in[2];
  const int*   edge_dst   = (const int*)d_in[3];
  const float* edge_attr  = (const float*)d_in[4];
  const float* ele        = (const float*)d_in[5];
  const float* sc_w0      = (const float*)d_in[6];
  const float* sc_w1      = (const float*)d_in[7];
  const float* l1_w0      = (const float*)d_in[8];
  const float* l1_w1      = (const float*)d_in[9];
  const float* fc_w0      = (const float*)d_in[10];
  const float* fc_w1      = (const float*)d_in[11];
  const float* l2_w0      = (const float*)d_in[12];
  const float* l2_w1      = (const float*)d_in[13];
  const float* l2_w2      = (const float*)d_in[14];
  float* out = (float*)d_out;

  char* base = (char*)d_ws;
  float* y              = (float*)(base);                       // 7.68 MB (stride 192)
  unsigned short* wbuf  = (unsigned short*)(base + 7680000);    // 102.4 MB packed
  float* ed2            = (float*)(base + 110080000);           // 12.8 MB (stride 20)
  int* counts           = (int*)(base + 122880000);
  int* offs             = (int*)(base + 122920000);
  int* cur              = (int*)(base + 122960000);
  int* order            = (int*)(base + 123000000);
  int* obeg             = (int*)(base + 123040000);
  int* ocnt             = (int*)(base + 123080000);
  int* dcur             = (int*)(base + 123120000);             // 1 KB
  unsigned short* fc1p  = (unsigned short*)(base + 123121024);  // 40 KB

  hipLaunchKernelGGL(k_init, dim3(80), dim3(256), 0, stream, counts, fc_w1, fc1p);
  hipLaunchKernelGGL(k_hist, dim3((N_EDGES + 255) / 256), dim3(256), 0, stream,
                     edge_dst, counts);
  hipLaunchKernelGGL(k_scan, dim3(1), dim3(256), 0, stream, counts, offs, cur, dcur);
  hipLaunchKernelGGL(k_perm, dim3(N_EDGES / 256), dim3(256), 0, stream,
                     edge_dst, cur, counts, offs, dcur, order, obeg, ocnt,
                     ele, edge_attr, edge_src, ed2);
  hipLaunchKernelGGL(k_mid, dim3(2500 + 6250), dim3(256), 0, stream,
                     ed2, fc_w0, fc1p, wbuf,
                     node_input, node_attr, l1_w0, l1_w1, y);
  hipLaunchKernelGGL(node_agg, dim3(2500), dim3(256), 0, stream,
                     y, node_input, node_attr, ed2, wbuf,
                     order, obeg, ocnt, sc_w0, sc_w1, l2_w0, l2_w1, l2_w2, out);
}